// Round 13
// baseline (328.222 us; speedup 1.0000x reference)
//
#include <hip/hip_runtime.h>
#include <cstdint>
#include <cstddef>

// ---------------------------------------------------------------------------
// GatingNetwork r13: ZERO-LDS, ZERO-BARRIER main loop. A fragments loaded
// per-lane straight from global (L1/L2 absorb the 4x intra-block duplication;
// 16x128B segments coalesce), split hi/lo in-register. No slab, no barriers:
// waves free-run, compiler pipelines loads without fence constraints --
// removes the structural barrier-drain stall (the ~105us dead time in r12).
// Keeps r12's proven pieces: 64x128 wave tiles (96 MFMA / A-fetch), rolling
// 2-set B pipe from L2 fragment-order images, 2 blocks/CU.
// Numerics (r1-r12 verified): A=64x hi/lo fp16, B=64w hi/lo fp16 (lo x2^8);
// 3-product Markidis MFMA 16x16x32; h at scale 2^12; fused LN/GELU/top2.
// ---------------------------------------------------------------------------

typedef _Float16 f16;
typedef _Float16 f16x8 __attribute__((ext_vector_type(8)));
typedef float f32x4 __attribute__((ext_vector_type(4)));

#define B_ROWS 65536
#define D_DIM 1024
#define H_DIM 512
#define E_DIM 8
#define BM 64
#define BK 32
#define THREADS 256
#define NCHUNK 32
#define IMG_CH (H_DIM * BK)              // 16384 halves per K-chunk B image
#define IMG_TOTAL (32 * IMG_CH)          // 1 MB per image
#define GACC_OFF ((size_t)2 * IMG_TOTAL * sizeof(f16))  // 2 MB

// ---- prep: split W1 into fp16 hi/lo images in MFMA B-fragment order --------
__global__ void prep_split(const float* __restrict__ W1,
                           f16* __restrict__ wh, f16* __restrict__ wl) {
  int id = blockIdx.x * 256 + threadIdx.x;   // 65536 threads
  int h = id & (H_DIM - 1);
  int kg = id >> 9;                          // 0..127
  int c = kg >> 2;
  int kk0 = (kg & 3) * 8;
  int k0 = kg * 8;
  f16x8 hv, lv;
#pragma unroll
  for (int j = 0; j < 8; ++j) {
    float v = W1[(size_t)(k0 + j) * H_DIM + h] * 64.0f;
    f16 hi = (f16)v;
    hv[j] = hi;
    lv[j] = (f16)((v - (float)hi) * 256.0f);  // residual pre-scaled 2^8
  }
  size_t o = (size_t)c * IMG_CH + (size_t)h * BK + kk0;
  *(f16x8*)&wh[o] = hv;
  *(f16x8*)&wl[o] = lv;
}

__global__ void zero_acc(float* __restrict__ acc) {
  if (threadIdx.x < 16) acc[threadIdx.x] = 0.0f;
}

// ---- main fused kernel -----------------------------------------------------
__global__ __launch_bounds__(THREADS, 2) void fused_main(
    const float* __restrict__ x,
    const f16* __restrict__ wh, const f16* __restrict__ wl,
    const float* __restrict__ b1, const float* __restrict__ lnw,
    const float* __restrict__ lnb, const float* __restrict__ W2,
    const float* __restrict__ b2, float* __restrict__ out,
    float* __restrict__ gacc) {
  // LDS used by the epilogue ONLY (GEMM is LDS-free).
  __shared__ __align__(16) char pool[35584];

  const int tid = threadIdx.x;
  const int lane = tid & 63;
  const int wv = tid >> 6;        // 0..3 : wave owns cols wv*128..+127, all 64 rows
  const int l15 = lane & 15;
  const int l4 = lane >> 4;       // 0..3
  const int64_t row0 = (int64_t)blockIdx.x * BM;

  // A lane base: rows (m*16 + l15), cols c*32 + l4*8 + 0..7 (fp32)
  const float* pax = x + (row0 + l15) * D_DIM + l4 * 8;

  // B lane base (fragment-order image, r2-verified): col = wv*128 + ...
  const f16* whp = wh + (wv * 128 + l15) * BK + l4 * 8;

  f32x4 acc[4][8];
#pragma unroll
  for (int m = 0; m < 4; ++m)
#pragma unroll
    for (int n = 0; n < 8; ++n) acc[m][n] = (f32x4){0.f, 0.f, 0.f, 0.f};

  // two half-chunk B register sets: [set][0..3]=hi frags, [4..7]=lo frags
  f16x8 setB[2][8];

#define ISSUE(si, C, half)                                                    \
  do {                                                                        \
    const f16* p = whp + (size_t)((C) & 31) * IMG_CH + (half) * 2048;         \
    setB[si][0] = *(const f16x8*)(p);                                         \
    setB[si][1] = *(const f16x8*)(p + 512);                                   \
    setB[si][2] = *(const f16x8*)(p + 1024);                                  \
    setB[si][3] = *(const f16x8*)(p + 1536);                                  \
    setB[si][4] = *(const f16x8*)(p + IMG_TOTAL);                             \
    setB[si][5] = *(const f16x8*)(p + IMG_TOTAL + 512);                       \
    setB[si][6] = *(const f16x8*)(p + IMG_TOTAL + 1024);                      \
    setB[si][7] = *(const f16x8*)(p + IMG_TOTAL + 1536);                      \
  } while (0)

  // one m-row of a 64-col half: ahs from ah (8 pk_mul) + 12 MFMA, acc
  // rotated across 4 n's (dependent spacing 4).
#define CH_M(si, NH, MM)                                                      \
  do {                                                                        \
    f16x8 ahs;                                                                \
    _Pragma("unroll") for (int q = 0; q < 8; ++q) ahs[q] =                    \
        ahf[MM][q] * (f16)0.00390625f;                                        \
    _Pragma("unroll") for (int n = 0; n < 4; ++n)                             \
      acc[MM][(NH)*4 + n] = __builtin_amdgcn_mfma_f32_16x16x32_f16(           \
          ahf[MM], setB[si][n], acc[MM][(NH)*4 + n], 0, 0, 0);                \
    _Pragma("unroll") for (int n = 0; n < 4; ++n)                             \
      acc[MM][(NH)*4 + n] = __builtin_amdgcn_mfma_f32_16x16x32_f16(           \
          alf[MM], setB[si][n], acc[MM][(NH)*4 + n], 0, 0, 0);                \
    _Pragma("unroll") for (int n = 0; n < 4; ++n)                             \
      acc[MM][(NH)*4 + n] = __builtin_amdgcn_mfma_f32_16x16x32_f16(           \
          ahs, setB[si][4 + n], acc[MM][(NH)*4 + n], 0, 0, 0);                \
  } while (0)

#define HALF(si, NH)                                                          \
  do {                                                                        \
    __builtin_amdgcn_s_setprio(1);                                            \
    CH_M(si, NH, 0);                                                          \
    CH_M(si, NH, 1);                                                          \
    CH_M(si, NH, 2);                                                          \
    CH_M(si, NH, 3);                                                          \
    __builtin_amdgcn_s_setprio(0);                                            \
  } while (0)

  // ---- prologue: B sets for chunk0 halves ---------------------------------
  ISSUE(0, 0, 0);
  ISSUE(1, 0, 1);

  f16x8 ahf[4], alf[4];
  for (int c = 0; c < NCHUNK; ++c) {
    // load + split this chunk's A fragments (per-lane, straight from L1/L2)
#pragma unroll
    for (int m = 0; m < 4; ++m) {
      const float* p = pax + m * (16 * D_DIM) + c * BK;
      float4 v0 = *(const float4*)p;
      float4 v1 = *(const float4*)(p + 4);
      float vv[8] = {v0.x, v0.y, v0.z, v0.w, v1.x, v1.y, v1.z, v1.w};
#pragma unroll
      for (int q = 0; q < 8; ++q) {
        float t = vv[q] * 64.0f;
        f16 hh = (f16)t;
        ahf[m][q] = hh;
        alf[m][q] = (f16)(t - (float)hh);
      }
    }
    HALF(0, 0);                   // cols wv*128+0..63   (set issued 1 chunk ago)
    ISSUE(0, c + 1, 0);           // refill set0 for chunk c+1
    HALF(1, 1);                   // cols wv*128+64..127
    ISSUE(1, c + 1, 1);           // refill set1 for chunk c+1
  }
#undef ISSUE
#undef CH_M
#undef HALF
  __syncthreads();  // epilogue LDS ordering

  // ---------------- epilogue (h at scale 2^12 in acc; r12-verified) ---------
  float* eW2T = (float*)pool;              // [512][12] padded = 24576 B
  float* eStat = (float*)(pool + 24576);   // [4][64][2] = 2048 B
  float* eLog = (float*)(pool + 26624);    // [4][64][8] = 8192 B
  float* eMu = (float*)(pool + 34816);     // [64]
  float* eRs = (float*)(pool + 35072);     // [64]
  float* eFP = (float*)(pool + 35328);     // [16]

  // stage W2 (256 threads cover 512 cols in 2 passes)
  for (int i = tid; i < H_DIM; i += THREADS) {
    float4 wa = *(const float4*)&W2[i * 8];
    float4 wb = *(const float4*)&W2[i * 8 + 4];
    *(float4*)&eW2T[i * 12] = wa;
    *(float4*)&eW2T[i * 12 + 4] = wb;
  }
  if (tid < 16) eFP[tid] = 0.0f;

  // h += b1 (scaled); per-column params from L2 (8 n-frags per thread)
  float bb[8], lw[8], lb[8];
#pragma unroll
  for (int n = 0; n < 8; ++n) {
    int col = wv * 128 + n * 16 + l15;
    bb[n] = b1[col] * 4096.0f;
    lw[n] = lnw[col];
    lb[n] = lnb[col];
#pragma unroll
    for (int m = 0; m < 4; ++m)
#pragma unroll
      for (int r = 0; r < 4; ++r) acc[m][n][r] += bb[n];
  }

  // row stats: partial over this wave's 128 cols, deterministic combine
#pragma unroll
  for (int m = 0; m < 4; ++m) {
    float s1[4] = {0, 0, 0, 0};
    float s2[4] = {0, 0, 0, 0};
#pragma unroll
    for (int n = 0; n < 8; ++n)
#pragma unroll
      for (int r = 0; r < 4; ++r) {
        float vv = acc[m][n][r];
        s1[r] += vv;
        s2[r] = fmaf(vv, vv, s2[r]);
      }
#pragma unroll
    for (int d = 1; d < 16; d <<= 1)
#pragma unroll
      for (int r = 0; r < 4; ++r) {
        s1[r] += __shfl_xor(s1[r], d);
        s2[r] += __shfl_xor(s2[r], d);
      }
    if (l15 == 0) {
      int rb = m * 16 + l4 * 4;
#pragma unroll
      for (int r = 0; r < 4; ++r) {
        eStat[(wv * 64 + rb + r) * 2 + 0] = s1[r];
        eStat[(wv * 64 + rb + r) * 2 + 1] = s2[r];
      }
    }
  }
  __syncthreads();
  if (tid < BM) {
    float s1 = 0.0f, s2 = 0.0f;
#pragma unroll
    for (int w = 0; w < 4; ++w) {
      s1 += eStat[(w * 64 + tid) * 2 + 0];
      s2 += eStat[(w * 64 + tid) * 2 + 1];
    }
    float mu = s1 * (1.0f / 512.0f);
    float var = s2 * (1.0f / 512.0f) - mu * mu;
    eMu[tid] = mu;
    eRs[tid] = 1.0f / sqrtf(var + (1e-5f * 4096.0f * 4096.0f));
  }
  __syncthreads();

  // LN + exact-erf GELU + per-wave partial logits (per-r accumulation)
#pragma unroll
  for (int m = 0; m < 4; ++m) {
    int rb = m * 16 + l4 * 4;
#pragma unroll
    for (int r = 0; r < 4; ++r) {
      float mu_r = eMu[rb + r];
      float rs_r = eRs[rb + r];
      float lg[8];
#pragma unroll
      for (int e = 0; e < 8; ++e) lg[e] = 0.0f;
#pragma unroll
      for (int n = 0; n < 8; ++n) {
        int col = wv * 128 + n * 16 + l15;
        float hn = (acc[m][n][r] - mu_r) * rs_r;
        float y = fmaf(hn, lw[n], lb[n]);
        float g = 0.5f * y * (1.0f + erff(y * 0.70710678118654752440f));
        float4 w0 = *(const float4*)&eW2T[col * 12];
        float4 w1 = *(const float4*)&eW2T[col * 12 + 4];
        lg[0] = fmaf(g, w0.x, lg[0]);
        lg[1] = fmaf(g, w0.y, lg[1]);
        lg[2] = fmaf(g, w0.z, lg[2]);
        lg[3] = fmaf(g, w0.w, lg[3]);
        lg[4] = fmaf(g, w1.x, lg[4]);
        lg[5] = fmaf(g, w1.y, lg[5]);
        lg[6] = fmaf(g, w1.z, lg[6]);
        lg[7] = fmaf(g, w1.w, lg[7]);
      }
#pragma unroll
      for (int d = 1; d < 16; d <<= 1)
#pragma unroll
        for (int e = 0; e < 8; ++e) lg[e] += __shfl_xor(lg[e], d);
      if (l15 == 0) {
#pragma unroll
        for (int e = 0; e < 8; ++e) eLog[(wv * 64 + rb + r) * 8 + e] = lg[e];
      }
    }
  }
  __syncthreads();

  // top-2 + sparse softmax + write + load-balance partials
  if (tid < BM) {
    float v[8];
#pragma unroll
    for (int e = 0; e < 8; ++e) {
      float s = b2[e];
#pragma unroll
      for (int w = 0; w < 4; ++w) s += eLog[(w * 64 + tid) * 8 + e];
      v[e] = s;
    }
    float m1 = v[0];
    int i1 = 0;
#pragma unroll
    for (int e = 1; e < 8; ++e)
      if (v[e] > m1) { m1 = v[e]; i1 = e; }   // strict >: lowest index wins ties
    float m2 = -3.0e38f;
    int i2 = -1;
#pragma unroll
    for (int e = 0; e < 8; ++e)
      if (e != i1 && v[e] > m2) { m2 = v[e]; i2 = e; }
    float dd = expf(m2 - m1);
    float inv = 1.0f / (1.0f + dd);
    float wA = inv, wB = dd * inv;
    float o[8];
#pragma unroll
    for (int e = 0; e < 8; ++e)
      o[e] = (e == i1) ? wA : ((e == i2) ? wB : 0.0f);
    float4* op = (float4*)&out[(row0 + tid) * 8];
    op[0] = (float4){o[0], o[1], o[2], o[3]};
    op[1] = (float4){o[4], o[5], o[6], o[7]};
    atomicAdd(&eFP[i1], 1.0f);
    atomicAdd(&eFP[i2], 1.0f);
    atomicAdd(&eFP[8 + i1], wA);
    atomicAdd(&eFP[8 + i2], wB);
  }
  __syncthreads();
  if (tid < 16) atomicAdd(&gacc[tid], eFP[tid]);
}

// ---- finalize load-balance loss --------------------------------------------
__global__ void lb_final(const float* __restrict__ gacc, float* __restrict__ out) {
  if (threadIdx.x == 0) {
    const float invB = 1.0f / 65536.0f;
    float s = 0.0f;
#pragma unroll
    for (int e = 0; e < 8; ++e) s += (gacc[e] * invB) * (gacc[8 + e] * invB);
    out[(size_t)B_ROWS * E_DIM] = 0.01f * 8.0f * s;
  }
}

// ---- launch ----------------------------------------------------------------
extern "C" void kernel_launch(void* const* d_in, const int* in_sizes, int n_in,
                              void* d_out, int out_size, void* d_ws, size_t ws_size,
                              hipStream_t stream) {
  (void)in_sizes; (void)n_in; (void)out_size; (void)ws_size;
  const float* x = (const float*)d_in[0];
  const float* W1 = (const float*)d_in[1];
  const float* b1 = (const float*)d_in[2];
  const float* lnw = (const float*)d_in[3];
  const float* lnb = (const float*)d_in[4];
  const float* W2 = (const float*)d_in[5];
  const float* b2 = (const float*)d_in[6];
  float* out = (float*)d_out;
  f16* wh = (f16*)d_ws;
  f16* wl = wh + IMG_TOTAL;
  float* gacc = (float*)((char*)d_ws + GACC_OFF);  // ws needs ~2.1 MB

  zero_acc<<<1, 64, 0, stream>>>(gacc);
  prep_split<<<(D_DIM * H_DIM / 8) / 256, 256, 0, stream>>>(W1, wh, wl);
  fused_main<<<B_ROWS / BM, THREADS, 0, stream>>>(x, wh, wl, b1, lnw, lnb, W2, b2,
                                                  out, gacc);
  lb_final<<<1, 64, 0, stream>>>(gacc, out);
}

// Round 14
// 240.579 us; speedup vs baseline: 1.3643x; 1.3643x over previous
//
#include <hip/hip_runtime.h>
#include <cstdint>
#include <cstddef>

// ---------------------------------------------------------------------------
// GatingNetwork r14: r12 (best, 242us) with the discovered redundancy fixed:
// r12's CH_M re-read the SAME A fragments for both column halves (16 ds_read
// + 64 pk_mul per chunk where 8 + 32 suffice). r14 fuses the halves per m:
// read ah/al once, ahs once, 24 MFMAs (12 per half, n-rotated). B-set refills
// at chunk tail, m=3 split so set0 refill lands before set1's last MFMAs
// (preserves ~300-500cyc issue-to-use distance > L2 ~200cyc).
// Everything else identical to r12: 64x128 wave tiles, per-chunk LDS A-slab,
// rolling 2-set B pipe from L2 fragment-order images, raw lgkm-only barriers,
// 2 blocks/CU.
// Numerics (r1-r13 verified): A=64x hi/lo fp16, B=64w hi/lo fp16 (lo x2^8);
// 3-product Markidis MFMA 16x16x32; h at scale 2^12; fused LN/GELU/top2.
// ---------------------------------------------------------------------------

typedef _Float16 f16;
typedef _Float16 f16x8 __attribute__((ext_vector_type(8)));
typedef float f32x4 __attribute__((ext_vector_type(4)));

#define B_ROWS 65536
#define D_DIM 1024
#define H_DIM 512
#define E_DIM 8
#define BM 64
#define BK 32
#define THREADS 256
#define NCHUNK 32
#define LDPX 40                          // slab row stride in halves (80 B)
#define SLABH 2560                       // 64 rows x 40 halves (one image)
#define BUFH 5120                        // hi + lo per buffer
#define IMG_CH (H_DIM * BK)              // 16384 halves per K-chunk B image
#define IMG_TOTAL (32 * IMG_CH)          // 1 MB per image
#define GACC_OFF ((size_t)2 * IMG_TOTAL * sizeof(f16))  // 2 MB

// ---- prep: split W1 into fp16 hi/lo images in MFMA B-fragment order --------
__global__ void prep_split(const float* __restrict__ W1,
                           f16* __restrict__ wh, f16* __restrict__ wl) {
  int id = blockIdx.x * 256 + threadIdx.x;   // 65536 threads
  int h = id & (H_DIM - 1);
  int kg = id >> 9;                          // 0..127
  int c = kg >> 2;
  int kk0 = (kg & 3) * 8;
  int k0 = kg * 8;
  f16x8 hv, lv;
#pragma unroll
  for (int j = 0; j < 8; ++j) {
    float v = W1[(size_t)(k0 + j) * H_DIM + h] * 64.0f;
    f16 hi = (f16)v;
    hv[j] = hi;
    lv[j] = (f16)((v - (float)hi) * 256.0f);  // residual pre-scaled 2^8
  }
  size_t o = (size_t)c * IMG_CH + (size_t)h * BK + kk0;
  *(f16x8*)&wh[o] = hv;
  *(f16x8*)&wl[o] = lv;
}

__global__ void zero_acc(float* __restrict__ acc) {
  if (threadIdx.x < 16) acc[threadIdx.x] = 0.0f;
}

// ---- main fused kernel -----------------------------------------------------
__global__ __launch_bounds__(THREADS, 2) void fused_main(
    const float* __restrict__ x,
    const f16* __restrict__ wh, const f16* __restrict__ wl,
    const float* __restrict__ b1, const float* __restrict__ lnw,
    const float* __restrict__ lnb, const float* __restrict__ W2,
    const float* __restrict__ b2, float* __restrict__ out,
    float* __restrict__ gacc) {
  // GEMM uses [0,20480) (2 x-slab buffers). Epilogue overlays [0,35584).
  __shared__ __align__(16) char pool[35584];
  f16* sx = (f16*)pool;

  const int tid = threadIdx.x;
  const int lane = tid & 63;
  const int wv = tid >> 6;        // 0..3 : wave owns cols wv*128..+127, all 64 rows
  const int l15 = lane & 15;
  const int l4 = lane >> 4;       // 0..3
  const int64_t row0 = (int64_t)blockIdx.x * BM;

  // staging: thread stages row tid>>2, 8 floats at k-offset (tid&3)*8
  const int srow = tid >> 2;
  const int koff = (tid & 3) * 8;
  const int swo = srow * LDPX + koff;
  const float* xbase = x + (row0 + srow) * D_DIM + koff;

  // B lane base (fragment-order image, r2-verified): col = wv*128 + ...
  const f16* whp = wh + (wv * 128 + l15) * BK + l4 * 8;

  f32x4 acc[4][8];
#pragma unroll
  for (int m = 0; m < 4; ++m)
#pragma unroll
    for (int n = 0; n < 8; ++n) acc[m][n] = (f32x4){0.f, 0.f, 0.f, 0.f};

  // two half-chunk B register sets: [set][0..3]=hi frags, [4..7]=lo frags
  f16x8 setB[2][8];

#define ISSUE(si, C, half)                                                    \
  do {                                                                        \
    const f16* p = whp + (size_t)((C) & 31) * IMG_CH + (half) * 2048;         \
    setB[si][0] = *(const f16x8*)(p);                                         \
    setB[si][1] = *(const f16x8*)(p + 512);                                   \
    setB[si][2] = *(const f16x8*)(p + 1024);                                  \
    setB[si][3] = *(const f16x8*)(p + 1536);                                  \
    setB[si][4] = *(const f16x8*)(p + IMG_TOTAL);                             \
    setB[si][5] = *(const f16x8*)(p + IMG_TOTAL + 512);                       \
    setB[si][6] = *(const f16x8*)(p + IMG_TOTAL + 1024);                      \
    setB[si][7] = *(const f16x8*)(p + IMG_TOTAL + 1536);                      \
  } while (0)

  // fused m-row: A read ONCE, ahs ONCE, 24 MFMAs (12 per half).
#define CHM(MM, bufv)                                                         \
  do {                                                                        \
    const int ao = (bufv)*BUFH + ((MM)*16 + l15) * LDPX + l4 * 8;             \
    f16x8 ah = *(const f16x8*)&sx[ao];                                        \
    f16x8 al = *(const f16x8*)&sx[ao + SLABH];                                \
    f16x8 ahs;                                                                \
    _Pragma("unroll") for (int q = 0; q < 8; ++q) ahs[q] =                    \
        ah[q] * (f16)0.00390625f;                                             \
    _Pragma("unroll") for (int n = 0; n < 4; ++n)                             \
      acc[MM][n] = __builtin_amdgcn_mfma_f32_16x16x32_f16(                    \
          ah, setB[0][n], acc[MM][n], 0, 0, 0);                               \
    _Pragma("unroll") for (int n = 0; n < 4; ++n)                             \
      acc[MM][4 + n] = __builtin_amdgcn_mfma_f32_16x16x32_f16(                \
          ah, setB[1][n], acc[MM][4 + n], 0, 0, 0);                           \
    _Pragma("unroll") for (int n = 0; n < 4; ++n)                             \
      acc[MM][n] = __builtin_amdgcn_mfma_f32_16x16x32_f16(                    \
          al, setB[0][n], acc[MM][n], 0, 0, 0);                               \
    _Pragma("unroll") for (int n = 0; n < 4; ++n)                             \
      acc[MM][4 + n] = __builtin_amdgcn_mfma_f32_16x16x32_f16(                \
          al, setB[1][n], acc[MM][4 + n], 0, 0, 0);                           \
    _Pragma("unroll") for (int n = 0; n < 4; ++n)                             \
      acc[MM][n] = __builtin_amdgcn_mfma_f32_16x16x32_f16(                    \
          ahs, setB[0][4 + n], acc[MM][n], 0, 0, 0);                          \
    _Pragma("unroll") for (int n = 0; n < 4; ++n)                             \
      acc[MM][4 + n] = __builtin_amdgcn_mfma_f32_16x16x32_f16(                \
          ahs, setB[1][4 + n], acc[MM][4 + n], 0, 0, 0);                      \
  } while (0)

#define WRITE_SLAB(bufv)                                                      \
  do {                                                                        \
    float vv[8] = {xv0.x, xv0.y, xv0.z, xv0.w, xv1.x, xv1.y, xv1.z, xv1.w};   \
    f16x8 hv, lv;                                                             \
    _Pragma("unroll") for (int q = 0; q < 8; ++q) {                           \
      float t = vv[q] * 64.0f;                                                \
      f16 hh = (f16)t;                                                        \
      hv[q] = hh;                                                             \
      lv[q] = (f16)(t - (float)hh);                                           \
    }                                                                         \
    *(f16x8*)&sx[(bufv)*BUFH + swo] = hv;                                     \
    *(f16x8*)&sx[(bufv)*BUFH + SLABH + swo] = lv;                             \
  } while (0)

  // raw barrier: drain only LDS ops, keep global loads in flight (T4)
#define SLAB_BARRIER()                                                        \
  do {                                                                        \
    asm volatile("s_waitcnt lgkmcnt(0)" ::: "memory");                        \
    __builtin_amdgcn_s_barrier();                                             \
    __builtin_amdgcn_sched_barrier(0);                                        \
  } while (0)

  // ---- prologue: slab chunk0, B sets for chunk0 halves, xv <- chunk1 ------
  float4 xv0 = *(const float4*)(xbase);
  float4 xv1 = *(const float4*)(xbase + 4);
  WRITE_SLAB(0);
  ISSUE(0, 0, 0);
  ISSUE(1, 0, 1);
  xv0 = *(const float4*)(xbase + 32);
  xv1 = *(const float4*)(xbase + 36);
  SLAB_BARRIER();

  for (int c = 0; c < NCHUNK; ++c) {
    const int buf = c & 1;
    __builtin_amdgcn_s_setprio(1);
    CHM(0, buf);
    CHM(1, buf);
    CHM(2, buf);
    // m=3 split: finish set0's uses, refill set0, finish set1's, refill set1
    {
      const int ao = buf * BUFH + (3 * 16 + l15) * LDPX + l4 * 8;
      f16x8 ah = *(const f16x8*)&sx[ao];
      f16x8 al = *(const f16x8*)&sx[ao + SLABH];
      f16x8 ahs;
#pragma unroll
      for (int q = 0; q < 8; ++q) ahs[q] = ah[q] * (f16)0.00390625f;
#pragma unroll
      for (int n = 0; n < 4; ++n)
        acc[3][n] = __builtin_amdgcn_mfma_f32_16x16x32_f16(ah, setB[0][n], acc[3][n], 0, 0, 0);
#pragma unroll
      for (int n = 0; n < 4; ++n)
        acc[3][n] = __builtin_amdgcn_mfma_f32_16x16x32_f16(al, setB[0][n], acc[3][n], 0, 0, 0);
#pragma unroll
      for (int n = 0; n < 4; ++n)
        acc[3][n] = __builtin_amdgcn_mfma_f32_16x16x32_f16(ahs, setB[0][4 + n], acc[3][n], 0, 0, 0);
      __builtin_amdgcn_s_setprio(0);
      ISSUE(0, c + 1, 0);           // refill set0 while set1's MFMAs run
      __builtin_amdgcn_s_setprio(1);
#pragma unroll
      for (int n = 0; n < 4; ++n)
        acc[3][4 + n] = __builtin_amdgcn_mfma_f32_16x16x32_f16(ah, setB[1][n], acc[3][4 + n], 0, 0, 0);
#pragma unroll
      for (int n = 0; n < 4; ++n)
        acc[3][4 + n] = __builtin_amdgcn_mfma_f32_16x16x32_f16(al, setB[1][n], acc[3][4 + n], 0, 0, 0);
#pragma unroll
      for (int n = 0; n < 4; ++n)
        acc[3][4 + n] = __builtin_amdgcn_mfma_f32_16x16x32_f16(ahs, setB[1][4 + n], acc[3][4 + n], 0, 0, 0);
      __builtin_amdgcn_s_setprio(0);
      ISSUE(1, c + 1, 1);           // refill set1; arrives during slab+barrier
    }
    WRITE_SLAB(buf ^ 1);          // slab chunk c+1 (xv loaded last iteration)
    xv0 = *(const float4*)(xbase + ((c + 2) & 31) * 32);     // x for chunk c+2
    xv1 = *(const float4*)(xbase + ((c + 2) & 31) * 32 + 4);
    SLAB_BARRIER();
  }
#undef ISSUE
#undef CHM
#undef WRITE_SLAB
#undef SLAB_BARRIER
  __syncthreads();  // full drain before overlaying epilogue LDS

  // ---------------- epilogue (h at scale 2^12 in acc; r12-verified) ---------
  float* eW2T = (float*)pool;              // [512][12] padded = 24576 B
  float* eStat = (float*)(pool + 24576);   // [4][64][2] = 2048 B
  float* eLog = (float*)(pool + 26624);    // [4][64][8] = 8192 B
  float* eMu = (float*)(pool + 34816);     // [64]
  float* eRs = (float*)(pool + 35072);     // [64]
  float* eFP = (float*)(pool + 35328);     // [16]

  // stage W2 (256 threads cover 512 cols in 2 passes)
  for (int i = tid; i < H_DIM; i += THREADS) {
    float4 wa = *(const float4*)&W2[i * 8];
    float4 wb = *(const float4*)&W2[i * 8 + 4];
    *(float4*)&eW2T[i * 12] = wa;
    *(float4*)&eW2T[i * 12 + 4] = wb;
  }
  if (tid < 16) eFP[tid] = 0.0f;

  // h += b1 (scaled); per-column params from L2 (8 n-frags per thread)
  float bb[8], lw[8], lb[8];
#pragma unroll
  for (int n = 0; n < 8; ++n) {
    int col = wv * 128 + n * 16 + l15;
    bb[n] = b1[col] * 4096.0f;
    lw[n] = lnw[col];
    lb[n] = lnb[col];
#pragma unroll
    for (int m = 0; m < 4; ++m)
#pragma unroll
      for (int r = 0; r < 4; ++r) acc[m][n][r] += bb[n];
  }

  // row stats: partial over this wave's 128 cols, deterministic combine
#pragma unroll
  for (int m = 0; m < 4; ++m) {
    float s1[4] = {0, 0, 0, 0};
    float s2[4] = {0, 0, 0, 0};
#pragma unroll
    for (int n = 0; n < 8; ++n)
#pragma unroll
      for (int r = 0; r < 4; ++r) {
        float vv = acc[m][n][r];
        s1[r] += vv;
        s2[r] = fmaf(vv, vv, s2[r]);
      }
#pragma unroll
    for (int d = 1; d < 16; d <<= 1)
#pragma unroll
      for (int r = 0; r < 4; ++r) {
        s1[r] += __shfl_xor(s1[r], d);
        s2[r] += __shfl_xor(s2[r], d);
      }
    if (l15 == 0) {
      int rb = m * 16 + l4 * 4;
#pragma unroll
      for (int r = 0; r < 4; ++r) {
        eStat[(wv * 64 + rb + r) * 2 + 0] = s1[r];
        eStat[(wv * 64 + rb + r) * 2 + 1] = s2[r];
      }
    }
  }
  __syncthreads();
  if (tid < BM) {
    float s1 = 0.0f, s2 = 0.0f;
#pragma unroll
    for (int w = 0; w < 4; ++w) {
      s1 += eStat[(w * 64 + tid) * 2 + 0];
      s2 += eStat[(w * 64 + tid) * 2 + 1];
    }
    float mu = s1 * (1.0f / 512.0f);
    float var = s2 * (1.0f / 512.0f) - mu * mu;
    eMu[tid] = mu;
    eRs[tid] = 1.0f / sqrtf(var + (1e-5f * 4096.0f * 4096.0f));
  }
  __syncthreads();

  // LN + exact-erf GELU + per-wave partial logits (per-r accumulation)
#pragma unroll
  for (int m = 0; m < 4; ++m) {
    int rb = m * 16 + l4 * 4;
#pragma unroll
    for (int r = 0; r < 4; ++r) {
      float mu_r = eMu[rb + r];
      float rs_r = eRs[rb + r];
      float lg[8];
#pragma unroll
      for (int e = 0; e < 8; ++e) lg[e] = 0.0f;
#pragma unroll
      for (int n = 0; n < 8; ++n) {
        int col = wv * 128 + n * 16 + l15;
        float hn = (acc[m][n][r] - mu_r) * rs_r;
        float y = fmaf(hn, lw[n], lb[n]);
        float g = 0.5f * y * (1.0f + erff(y * 0.70710678118654752440f));
        float4 w0 = *(const float4*)&eW2T[col * 12];
        float4 w1 = *(const float4*)&eW2T[col * 12 + 4];
        lg[0] = fmaf(g, w0.x, lg[0]);
        lg[1] = fmaf(g, w0.y, lg[1]);
        lg[2] = fmaf(g, w0.z, lg[2]);
        lg[3] = fmaf(g, w0.w, lg[3]);
        lg[4] = fmaf(g, w1.x, lg[4]);
        lg[5] = fmaf(g, w1.y, lg[5]);
        lg[6] = fmaf(g, w1.z, lg[6]);
        lg[7] = fmaf(g, w1.w, lg[7]);
      }
#pragma unroll
      for (int d = 1; d < 16; d <<= 1)
#pragma unroll
        for (int e = 0; e < 8; ++e) lg[e] += __shfl_xor(lg[e], d);
      if (l15 == 0) {
#pragma unroll
        for (int e = 0; e < 8; ++e) eLog[(wv * 64 + rb + r) * 8 + e] = lg[e];
      }
    }
  }
  __syncthreads();

  // top-2 + sparse softmax + write + load-balance partials
  if (tid < BM) {
    float v[8];
#pragma unroll
    for (int e = 0; e < 8; ++e) {
      float s = b2[e];
#pragma unroll
      for (int w = 0; w < 4; ++w) s += eLog[(w * 64 + tid) * 8 + e];
      v[e] = s;
    }
    float m1 = v[0];
    int i1 = 0;
#pragma unroll
    for (int e = 1; e < 8; ++e)
      if (v[e] > m1) { m1 = v[e]; i1 = e; }   // strict >: lowest index wins ties
    float m2 = -3.0e38f;
    int i2 = -1;
#pragma unroll
    for (int e = 0; e < 8; ++e)
      if (e != i1 && v[e] > m2) { m2 = v[e]; i2 = e; }
    float dd = expf(m2 - m1);
    float inv = 1.0f / (1.0f + dd);
    float wA = inv, wB = dd * inv;
    float o[8];
#pragma unroll
    for (int e = 0; e < 8; ++e)
      o[e] = (e == i1) ? wA : ((e == i2) ? wB : 0.0f);
    float4* op = (float4*)&out[(row0 + tid) * 8];
    op[0] = (float4){o[0], o[1], o[2], o[3]};
    op[1] = (float4){o[4], o[5], o[6], o[7]};
    atomicAdd(&eFP[i1], 1.0f);
    atomicAdd(&eFP[i2], 1.0f);
    atomicAdd(&eFP[8 + i1], wA);
    atomicAdd(&eFP[8 + i2], wB);
  }
  __syncthreads();
  if (tid < 16) atomicAdd(&gacc[tid], eFP[tid]);
}

// ---- finalize load-balance loss --------------------------------------------
__global__ void lb_final(const float* __restrict__ gacc, float* __restrict__ out) {
  if (threadIdx.x == 0) {
    const float invB = 1.0f / 65536.0f;
    float s = 0.0f;
#pragma unroll
    for (int e = 0; e < 8; ++e) s += (gacc[e] * invB) * (gacc[8 + e] * invB);
    out[(size_t)B_ROWS * E_DIM] = 0.01f * 8.0f * s;
  }
}

// ---- launch ----------------------------------------------------------------
extern "C" void kernel_launch(void* const* d_in, const int* in_sizes, int n_in,
                              void* d_out, int out_size, void* d_ws, size_t ws_size,
                              hipStream_t stream) {
  (void)in_sizes; (void)n_in; (void)out_size; (void)ws_size;
  const float* x = (const float*)d_in[0];
  const float* W1 = (const float*)d_in[1];
  const float* b1 = (const float*)d_in[2];
  const float* lnw = (const float*)d_in[3];
  const float* lnb = (const float*)d_in[4];
  const float* W2 = (const float*)d_in[5];
  const float* b2 = (const float*)d_in[6];
  float* out = (float*)d_out;
  f16* wh = (f16*)d_ws;
  f16* wl = wh + IMG_TOTAL;
  float* gacc = (float*)((char*)d_ws + GACC_OFF);  // ws needs ~2.1 MB

  zero_acc<<<1, 64, 0, stream>>>(gacc);
  prep_split<<<(D_DIM * H_DIM / 8) / 256, 256, 0, stream>>>(W1, wh, wl);
  fused_main<<<B_ROWS / BM, THREADS, 0, stream>>>(x, wh, wl, b1, lnw, lnb, W2, b2,
                                                  out, gacc);
  lb_final<<<1, 64, 0, stream>>>(gacc, out);
}